// Round 6
// baseline (354.186 us; speedup 1.0000x reference)
//
#include <hip/hip_runtime.h>

// Problem constants: B=8, T=1024, D=1024, H=16, HD=64
#define BT   8192     // B*T (GEMM M)
#define DD   1024     // model dim (GEMM N=K)
#define TT   1024     // sequence length
#define NHD  64       // head dim
// SCALE * log2(e) = 0.125 * 1.4426950408889634
#define CEXP 0.18033688011112042f

typedef unsigned short bf16_t;
typedef __attribute__((ext_vector_type(8))) short bf16x8;
typedef __attribute__((ext_vector_type(4))) float f32x4;

struct CvtArgs {
  const float* src[7];
  bf16_t*      dst[7];
  int          n8[7];
};

struct GemmArgs {
  const bf16_t* A[3];
  const bf16_t* Bw[3];
  const float*  bias[3];
  void*         C[3];
};

__device__ __forceinline__ unsigned short f2b(float f) {
  union { float f; unsigned u; } v; v.f = f;
  unsigned u = v.u;
  return (unsigned short)((u + 0x7FFFu + ((u >> 16) & 1u)) >> 16);  // RNE
}

__device__ __forceinline__ unsigned cvt_pk(float lo, float hi) {
  unsigned r;
  asm("v_cvt_pk_bf16_f32 %0, %1, %2" : "=v"(r) : "v"(lo), "v"(hi));
  return r;
}

__device__ __forceinline__ float exp2_fast(float x) {
  float r;
  asm("v_exp_f32 %0, %1" : "=v"(r) : "v"(x));
  return r;
}

__device__ __forceinline__ void gload_lds16(const void* g, void* l) {
  __builtin_amdgcn_global_load_lds(
      (const __attribute__((address_space(1))) unsigned int*)g,
      (__attribute__((address_space(3))) unsigned int*)l, 16, 0, 0);
}

#define LGKM0() do { asm volatile("s_waitcnt lgkmcnt(0)" ::: "memory"); \
                     __builtin_amdgcn_sched_barrier(0); } while (0)
#define BARRIER() do { asm volatile("" ::: "memory"); \
                       __builtin_amdgcn_s_barrier(); \
                       asm volatile("" ::: "memory"); } while (0)

// ---------------- f32 -> bf16 conversion (7 arrays, z-indexed) ----------------
__global__ void cvt_kernel(CvtArgs a) {
  const int z = blockIdx.z;
  const float* __restrict__ s = a.src[z];
  bf16_t* __restrict__ d = a.dst[z];
  const int n8 = a.n8[z];
  for (int i = blockIdx.x * blockDim.x + threadIdx.x; i < n8;
       i += gridDim.x * blockDim.x) {
    const float4* sp = (const float4*)s + (size_t)i * 2;
    float4 x = sp[0], y = sp[1];
    union { unsigned short h[8]; uint4 v; } u;
    u.h[0] = f2b(x.x); u.h[1] = f2b(x.y); u.h[2] = f2b(x.z); u.h[3] = f2b(x.w);
    u.h[4] = f2b(y.x); u.h[5] = f2b(y.y); u.h[6] = f2b(y.z); u.h[7] = f2b(y.w);
    *((uint4*)(d + (size_t)i * 8)) = u.v;
  }
}

// ---------------- NT bf16 GEMM, 256x256 tile, BK=32, 4-deep LDS pipeline -----
// C[i,j] = sum_k A[i,k]*Bw[j,k] + bias[j].  512 thr = 8 waves (2M x 4N),
// wave tile 128x64, acc[8][4] f32x4.  4 LDS buffers x 32KB (A 16K + B 16K).
// LDS layout (per buffer, per matrix): element (r,k), r<256, k<32:
//   sr=r>>1, slot=((r&1)*4 + k/8) ^ (sr&7), byte = sr*128 + slot*16 + (k%8)*2
// -> frag ds_read_b128 lands 2 lanes/bank (free); staging is linear
//    global_load_lds with inverse-permuted global source (both-sides swizzle).
// Pipeline: prefetch 3 K-tiles ahead; per tile s_waitcnt vmcnt(8) (counted,
// never 0 until the tail), raw s_barrier, 4 sub-phases of
// {ds_read || 1 stage load || lgkmcnt(0) || setprio(1) + 8 MFMA}.
template<bool F32OUT>
__global__ __launch_bounds__(512, 2) void gemm256(GemmArgs g) {
  extern __shared__ char lds[];
  constexpr int K = DD, N = DD;
  const int z = blockIdx.z;
  const bf16_t* __restrict__ A  = g.A[z];
  const bf16_t* __restrict__ Bw = g.Bw[z];
  const float*  __restrict__ bias = g.bias[z];
  const int tid = threadIdx.x, lane = tid & 63, wid = tid >> 6;
  const int wr = wid >> 2, wc = wid & 3;
  const int g4 = lane >> 4, q15 = lane & 15;
  const int brow = blockIdx.y * 256, bcol = blockIdx.x * 256;

  // staging decode: 4 parts/thread (A i=0,1 ; B i=0,1), 16B each.
  // linear chunk idx = wid*128 + i*64 + lane  ->  inverse of the LDS swizzle.
  const bf16_t* srcA[2];
  const bf16_t* srcB[2];
#pragma unroll
  for (int i = 0; i < 2; ++i) {
    int idx = wid * 128 + i * 64 + lane;
    int sr = idx >> 3, ssw = idx & 7;
    int sl = ssw ^ (sr & 7);
    int r  = sr * 2 + (sl >> 2);
    int k0 = (sl & 3) * 8;
    srcA[i] = A  + (size_t)(brow + r) * K + k0;
    srcB[i] = Bw + (size_t)(bcol + r) * K + k0;
  }

  auto stagePart = [&](int kt, int p) {
    const int bufo = (kt & 3) << 15;
    const int i = p & 1;
    const bf16_t* s = (p < 2 ? srcA[i] : srcB[i]) + kt * 32;
    char* d = lds + bufo + (p < 2 ? 0 : 16384) + wid * 2048 + i * 1024;
    gload_lds16(s, d);  // hw adds lane*16
  };

  // frag read byte-offsets (within a buffer)
  int offA[2][4], offB[2][2];
#pragma unroll
  for (int mh = 0; mh < 2; ++mh)
#pragma unroll
    for (int mm = 0; mm < 4; ++mm) {
      int row = wr * 128 + mh * 64 + mm * 16 + q15;
      offA[mh][mm] = (row >> 1) * 128 +
                     (((((row & 1) << 2) + g4) ^ ((row >> 1) & 7)) << 4);
    }
#pragma unroll
  for (int nh = 0; nh < 2; ++nh)
#pragma unroll
    for (int nn = 0; nn < 2; ++nn) {
      int row = wc * 64 + nh * 32 + nn * 16 + q15;
      offB[nh][nn] = 16384 + (row >> 1) * 128 +
                     (((((row & 1) << 2) + g4) ^ ((row >> 1) & 7)) << 4);
    }

  f32x4 acc[8][4];
#pragma unroll
  for (int m = 0; m < 8; ++m)
#pragma unroll
    for (int n = 0; n < 4; ++n) acc[m][n] = (f32x4){0.f, 0.f, 0.f, 0.f};

  // prologue: stage tiles 0..2 (12 loads in flight)
#pragma unroll
  for (int t = 0; t < 3; ++t)
#pragma unroll
    for (int p = 0; p < 4; ++p) stagePart(t, p);

  bf16x8 af[4], bfA[2], bfB[2];

  auto body = [&](int kt, bool doStage) {
    const int bufo = (kt & 3) << 15;
    // sp0: A half0 + B half0
#pragma unroll
    for (int mm = 0; mm < 4; ++mm)
      af[mm] = *(const bf16x8*)(lds + bufo + offA[0][mm]);
#pragma unroll
    for (int nn = 0; nn < 2; ++nn)
      bfA[nn] = *(const bf16x8*)(lds + bufo + offB[0][nn]);
    if (doStage) stagePart(kt + 3, 0);
    LGKM0();
    __builtin_amdgcn_s_setprio(1);
#pragma unroll
    for (int mm = 0; mm < 4; ++mm)
#pragma unroll
      for (int nn = 0; nn < 2; ++nn)
        acc[mm][nn] = __builtin_amdgcn_mfma_f32_16x16x32_bf16(
            af[mm], bfA[nn], acc[mm][nn], 0, 0, 0);
    __builtin_amdgcn_s_setprio(0);
    // sp1: B half1
#pragma unroll
    for (int nn = 0; nn < 2; ++nn)
      bfB[nn] = *(const bf16x8*)(lds + bufo + offB[1][nn]);
    if (doStage) stagePart(kt + 3, 1);
    LGKM0();
    __builtin_amdgcn_s_setprio(1);
#pragma unroll
    for (int mm = 0; mm < 4; ++mm)
#pragma unroll
      for (int nn = 0; nn < 2; ++nn)
        acc[mm][2 + nn] = __builtin_amdgcn_mfma_f32_16x16x32_bf16(
            af[mm], bfB[nn], acc[mm][2 + nn], 0, 0, 0);
    __builtin_amdgcn_s_setprio(0);
    // sp2: A half1
#pragma unroll
    for (int mm = 0; mm < 4; ++mm)
      af[mm] = *(const bf16x8*)(lds + bufo + offA[1][mm]);
    if (doStage) stagePart(kt + 3, 2);
    LGKM0();
    __builtin_amdgcn_s_setprio(1);
#pragma unroll
    for (int mm = 0; mm < 4; ++mm)
#pragma unroll
      for (int nn = 0; nn < 2; ++nn)
        acc[4 + mm][nn] = __builtin_amdgcn_mfma_f32_16x16x32_bf16(
            af[mm], bfA[nn], acc[4 + mm][nn], 0, 0, 0);
    __builtin_amdgcn_s_setprio(0);
    // sp3
    if (doStage) stagePart(kt + 3, 3);
    __builtin_amdgcn_s_setprio(1);
#pragma unroll
    for (int mm = 0; mm < 4; ++mm)
#pragma unroll
      for (int nn = 0; nn < 2; ++nn)
        acc[4 + mm][2 + nn] = __builtin_amdgcn_mfma_f32_16x16x32_bf16(
            af[mm], bfB[nn], acc[4 + mm][2 + nn], 0, 0, 0);
    __builtin_amdgcn_s_setprio(0);
  };

  // main loop: tiles 0..29 with steady-state counted wait vmcnt(8);
  // stages are issued for kt+3 while computing kt (4 distinct buffers).
#pragma unroll 1
  for (int kt = 0; kt < 30; ++kt) {
    asm volatile("s_waitcnt vmcnt(8)" ::: "memory");  // tile kt's 4 loads done
    BARRIER();
    body(kt, kt < 29);
    BARRIER();  // all reads of buf[kt&3] done before it is restaged
  }
  {
    asm volatile("s_waitcnt vmcnt(4)" ::: "memory");
    BARRIER();
    body(30, false);
    BARRIER();
  }
  {
    asm volatile("s_waitcnt vmcnt(0)" ::: "memory");
    BARRIER();
    body(31, false);
    BARRIER();
  }

  // epilogue
  float bv[2][2];
#pragma unroll
  for (int nh = 0; nh < 2; ++nh)
#pragma unroll
    for (int nn = 0; nn < 2; ++nn)
      bv[nh][nn] = bias[bcol + wc * 64 + nh * 32 + nn * 16 + q15];
#pragma unroll
  for (int mh = 0; mh < 2; ++mh)
#pragma unroll
    for (int mm = 0; mm < 4; ++mm)
#pragma unroll
      for (int nh = 0; nh < 2; ++nh)
#pragma unroll
        for (int nn = 0; nn < 2; ++nn) {
          const int col = bcol + wc * 64 + nh * 32 + nn * 16 + q15;
#pragma unroll
          for (int r = 0; r < 4; ++r) {
            const int row = brow + wr * 128 + mh * 64 + mm * 16 + g4 * 4 + r;
            float v = acc[mh * 4 + mm][nh * 2 + nn][r] + bv[nh][nn];
            if (F32OUT)
              ((float*)g.C[z])[(size_t)row * N + col] = v;
            else
              ((bf16_t*)g.C[z])[(size_t)row * N + col] = f2b(v);
          }
        }
}

// ---------------- V transpose: Vp[b*T+t][h*64+d] -> Vt[(b*16+h)*64+d][t] ----
__global__ __launch_bounds__(256) void vt_kernel(const bf16_t* __restrict__ Vp,
                                                 bf16_t* __restrict__ Vt) {
  __shared__ bf16_t tile[64][72];
  const int bh = blockIdx.y, b = bh >> 4, h = bh & 15;
  const int t0 = blockIdx.x * 64;
  const int tid = threadIdx.x;
  const int r = tid >> 3, c8 = (tid & 7) * 8;
#pragma unroll
  for (int i = 0; i < 2; ++i) {
    int row = i * 32 + r;
    uint4 v = *(const uint4*)(Vp + (size_t)(b * TT + t0 + row) * DD + h * NHD + c8);
    *(uint4*)&tile[row][c8] = v;
  }
  __syncthreads();
#pragma unroll
  for (int i = 0; i < 2; ++i) {
    int d = i * 32 + r;
    union { bf16_t e[8]; uint4 v; } w;
#pragma unroll
    for (int j = 0; j < 8; ++j) w.e[j] = tile[c8 + j][d];
    *(uint4*)(Vt + ((size_t)bh * NHD + d) * TT + t0 + c8) = w.v;
  }
}

// ---------------- flash attention (unchanged — verified round 4) -------------
__global__ __launch_bounds__(256, 4) void attn_kernel(
    const bf16_t* __restrict__ Qg, const bf16_t* __restrict__ Kg,
    const bf16_t* __restrict__ VtG, bf16_t* __restrict__ Og) {
  const int qt = blockIdx.x;
  const int bh = blockIdx.y;
  const int b = bh >> 4, h = bh & 15;
  const int tid = threadIdx.x, lane = tid & 63, wid = tid >> 6;
  const int g = lane >> 4, q15 = lane & 15;
  const size_t baseQK = ((size_t)b * TT) * DD + (size_t)h * NHD;
  const size_t baseV  = (size_t)bh * NHD * TT;
  const int q0 = qt * 64;

  __shared__ bf16_t Qs[64 * 64];
  __shared__ bf16_t Ks[2][64 * 64];
  __shared__ bf16_t Vs[2][64 * 64];

  const int srow = wid * 8 + (lane >> 3);
  const int sslot0 = lane & 7;

#pragma unroll
  for (int q = 0; q < 2; ++q) {
    int r = q * 32 + srow;
    int sc = (sslot0 ^ (r & 7)) * 8;
    gload_lds16(Qg + baseQK + (size_t)(q0 + r) * DD + sc,
                (char*)Qs + q * 4096 + wid * 1024);
  }

  auto stageKV = [&](int kt, int buf) {
#pragma unroll
    for (int q = 0; q < 2; ++q) {
      int r = q * 32 + srow;
      int sc = (sslot0 ^ (r & 7)) * 8;
      gload_lds16(Kg + baseQK + (size_t)(kt * 64 + r) * DD + sc,
                  (char*)Ks[buf] + q * 4096 + wid * 1024);
      gload_lds16(VtG + baseV + (size_t)r * TT + kt * 64 + sc,
                  (char*)Vs[buf] + q * 4096 + wid * 1024);
    }
  };
  stageKV(0, 0);

  float mreg = -1e30f, lsum = 0.f;
  f32x4 o[4];
#pragma unroll
  for (int n = 0; n < 4; ++n) o[n] = (f32x4){0.f, 0.f, 0.f, 0.f};
  bf16x8 aq[2];

  const int shsrc0 = q15 + ((lane & 16) << 1);
  const bool up = (lane & 32) != 0;

  for (int kt = 0; kt < 16; ++kt) {
    __syncthreads();
    if (kt == 0) {
      int qrow = wid * 16 + q15;
#pragma unroll
      for (int ks = 0; ks < 2; ++ks) {
        int slot = (ks * 4 + g) ^ (qrow & 7);
        aq[ks] = *(const bf16x8*)((const char*)Qs + qrow * 128 + slot * 16);
      }
    }
    if (kt + 1 < 16) stageKV(kt + 1, (kt + 1) & 1);
    const char* K_ = (const char*)Ks[kt & 1];
    const char* V_ = (const char*)Vs[kt & 1];

    f32x4 s[4];
#pragma unroll
    for (int n = 0; n < 4; ++n) s[n] = (f32x4){0.f, 0.f, 0.f, 0.f};
#pragma unroll
    for (int ks = 0; ks < 2; ++ks) {
#pragma unroll
      for (int n = 0; n < 4; ++n) {
        int krow = n * 16 + q15;
        int slot = (ks * 4 + g) ^ (krow & 7);
        bf16x8 ak = *(const bf16x8*)(K_ + krow * 128 + slot * 16);
        s[n] = __builtin_amdgcn_mfma_f32_16x16x32_bf16(ak, aq[ks], s[n], 0, 0, 0);
      }
    }

    float vmax = s[0][0];
#pragma unroll
    for (int n = 0; n < 4; ++n)
#pragma unroll
      for (int r = 0; r < 4; ++r) vmax = fmaxf(vmax, s[n][r]);
    vmax = fmaxf(vmax, __shfl_xor(vmax, 16));
    vmax = fmaxf(vmax, __shfl_xor(vmax, 32));
    float nm = fmaxf(mreg, vmax);
    float bco = -nm * CEXP;
    float rs = 0.f;
#pragma unroll
    for (int n = 0; n < 4; ++n)
#pragma unroll
      for (int r = 0; r < 4; ++r) {
        s[n][r] = exp2_fast(s[n][r] * CEXP + bco);
        rs += s[n][r];
      }
    rs += __shfl_xor(rs, 16);
    rs += __shfl_xor(rs, 32);
    float fac = exp2_fast(mreg * CEXP + bco);
    mreg = nm;
    lsum = lsum * fac + rs;

    float frow[4];
#pragma unroll
    for (int r = 0; r < 4; ++r) frow[r] = __shfl(fac, g * 4 + r);
#pragma unroll
    for (int n = 0; n < 4; ++n)
#pragma unroll
      for (int r = 0; r < 4; ++r) o[n][r] *= frow[r];

    unsigned pk[4][2];
#pragma unroll
    for (int n = 0; n < 4; ++n) {
      pk[n][0] = cvt_pk(s[n][0], s[n][1]);
      pk[n][1] = cvt_pk(s[n][2], s[n][3]);
    }
    bf16x8 ap[2];
#pragma unroll
    for (int c = 0; c < 2; ++c) {
      unsigned lo0 = (unsigned)__shfl((int)pk[2 * c][0], shsrc0);
      unsigned lo1 = (unsigned)__shfl((int)pk[2 * c][1], shsrc0);
      unsigned lo2 = (unsigned)__shfl((int)pk[2 * c][0], shsrc0 + 16);
      unsigned lo3 = (unsigned)__shfl((int)pk[2 * c][1], shsrc0 + 16);
      unsigned hi0 = (unsigned)__shfl((int)pk[2 * c + 1][0], shsrc0);
      unsigned hi1 = (unsigned)__shfl((int)pk[2 * c + 1][1], shsrc0);
      unsigned hi2 = (unsigned)__shfl((int)pk[2 * c + 1][0], shsrc0 + 16);
      unsigned hi3 = (unsigned)__shfl((int)pk[2 * c + 1][1], shsrc0 + 16);
      union { unsigned u[4]; bf16x8 v; } t;
      t.u[0] = up ? hi0 : lo0;
      t.u[1] = up ? hi1 : lo1;
      t.u[2] = up ? hi2 : lo2;
      t.u[3] = up ? hi3 : lo3;
      ap[c] = t.v;
    }

#pragma unroll
    for (int c = 0; c < 2; ++c) {
#pragma unroll
      for (int nd = 0; nd < 4; ++nd) {
        int vrow = nd * 16 + q15;
        int slot = (c * 4 + g) ^ (vrow & 7);
        bf16x8 bv = *(const bf16x8*)(V_ + vrow * 128 + slot * 16);
        o[nd] = __builtin_amdgcn_mfma_f32_16x16x32_bf16(ap[c], bv, o[nd], 0, 0, 0);
      }
    }
  }

  float lrow[4];
#pragma unroll
  for (int r = 0; r < 4; ++r) lrow[r] = 1.f / __shfl(lsum, g * 4 + r);
#pragma unroll
  for (int nd = 0; nd < 4; ++nd)
#pragma unroll
    for (int r = 0; r < 4; ++r) {
      int row = q0 + wid * 16 + g * 4 + r;
      int col = nd * 16 + q15;
      Og[baseQK + (size_t)row * DD + col] = f2b(o[nd][r] * lrow[r]);
    }
}

// ---------------- host glue ----------------
extern "C" void kernel_launch(void* const* d_in, const int* in_sizes, int n_in,
                              void* d_out, int out_size, void* d_ws, size_t ws_size,
                              hipStream_t stream) {
  const float* q_in = (const float*)d_in[0];
  const float* k_in = (const float*)d_in[1];
  const float* v_in = (const float*)d_in[2];
  const float* Wq = (const float*)d_in[5];
  const float* bq = (const float*)d_in[6];
  const float* Wk = (const float*)d_in[7];
  const float* bk = (const float*)d_in[8];
  const float* Wv = (const float*)d_in[9];
  const float* bv = (const float*)d_in[10];
  const float* Wo = (const float*)d_in[11];
  const float* bo = (const float*)d_in[12];
  float* out = (float*)d_out;

  char* ws = (char*)d_ws;
  const size_t SZX = (size_t)BT * DD * 2;   // 16 MiB
  const size_t SZW = (size_t)DD * DD * 2;   // 2 MiB
  bf16_t* Xq  = (bf16_t*)(ws);
  bf16_t* Xk  = (bf16_t*)(ws + SZX);
  bf16_t* Xv  = (bf16_t*)(ws + 2 * SZX);
  bf16_t* Wqb = (bf16_t*)(ws + 3 * SZX);
  bf16_t* Wkb = (bf16_t*)(ws + 3 * SZX + SZW);
  bf16_t* Wvb = (bf16_t*)(ws + 3 * SZX + 2 * SZW);
  bf16_t* Wob = (bf16_t*)(ws + 3 * SZX + 3 * SZW);
  bf16_t* Qp  = (bf16_t*)(ws + 3 * SZX + 4 * SZW);
  bf16_t* Kp  = Qp + (size_t)BT * DD;
  bf16_t* Vp  = Kp + (size_t)BT * DD;
  bf16_t* attn = Xq;  // Xq dead after projections
  bf16_t* Vt   = Xk;  // Xk dead after projections

  // allow 128KB dynamic LDS for the GEMMs (host-side attribute, capture-safe)
  hipFuncSetAttribute((const void*)gemm256<false>,
                      hipFuncAttributeMaxDynamicSharedMemorySize, 131072);
  hipFuncSetAttribute((const void*)gemm256<true>,
                      hipFuncAttributeMaxDynamicSharedMemorySize, 131072);

  CvtArgs ca;
  ca.src[0] = q_in; ca.dst[0] = Xq;  ca.n8[0] = BT * DD / 8;
  ca.src[1] = k_in; ca.dst[1] = Xk;  ca.n8[1] = BT * DD / 8;
  ca.src[2] = v_in; ca.dst[2] = Xv;  ca.n8[2] = BT * DD / 8;
  ca.src[3] = Wq;   ca.dst[3] = Wqb; ca.n8[3] = DD * DD / 8;
  ca.src[4] = Wk;   ca.dst[4] = Wkb; ca.n8[4] = DD * DD / 8;
  ca.src[5] = Wv;   ca.dst[5] = Wvb; ca.n8[5] = DD * DD / 8;
  ca.src[6] = Wo;   ca.dst[6] = Wob; ca.n8[6] = DD * DD / 8;
  cvt_kernel<<<dim3(512, 1, 7), 256, 0, stream>>>(ca);

  GemmArgs gp;
  gp.A[0] = Xq; gp.A[1] = Xk; gp.A[2] = Xv;
  gp.Bw[0] = Wqb; gp.Bw[1] = Wkb; gp.Bw[2] = Wvb;
  gp.bias[0] = bq; gp.bias[1] = bk; gp.bias[2] = bv;
  gp.C[0] = Qp; gp.C[1] = Kp; gp.C[2] = Vp;
  gemm256<false><<<dim3(DD / 256, BT / 256, 3), 512, 131072, stream>>>(gp);

  vt_kernel<<<dim3(TT / 64, 128), 256, 0, stream>>>(Vp, Vt);

  attn_kernel<<<dim3(TT / 64, 128), 256, 0, stream>>>(Qp, Kp, Vt, attn);

  GemmArgs go;
  go.A[0] = attn; go.A[1] = attn; go.A[2] = attn;
  go.Bw[0] = Wob; go.Bw[1] = Wob; go.Bw[2] = Wob;
  go.bias[0] = bo; go.bias[1] = bo; go.bias[2] = bo;
  go.C[0] = out; go.C[1] = out; go.C[2] = out;
  gemm256<true><<<dim3(DD / 256, BT / 256, 1), 512, 131072, stream>>>(go);
}